// Round 23
// baseline (64.231 us; speedup 1.0000x reference)
//
#include <hip/hip_runtime.h>

#define NROWS 8192
#define DDIM  64
#define KNN   32
#define MAXIT 100

// alpha/beta arrive as 1-element arrays; robust to int32 or float32 encoding.
__device__ __forceinline__ float scalar_val(const void* p) {
    int iv = *(const int*)p;
    if (iv > -1000000 && iv < 1000000) return (float)iv;
    return *(const float*)p;
}

// R16 champion structure (56.8us) + phase-stagger: half the blocks sleep
// ~10us before running the IDENTICAL program, so their front (L3-read-bound)
// overlaps the other half's A-stream drain (HBM-write-bound) instead of the
// whole fleet running front/stream in lockstep. No ordering, no races, no
// conditional stores -- just a time offset.
__global__ __launch_bounds__(256, 4) void school_fused_kernel(
    const float* __restrict__ Y,
    const float* __restrict__ semH,
    const float* __restrict__ orthoH,
    const int*   __restrict__ idx,
    const void*  alpha_p,
    const void*  beta_p,
    float* __restrict__ embs,   // N*D
    float* __restrict__ A,      // N*N
    float* __restrict__ Yout)   // N*D
{
    // ---- phase stagger: delay half the fleet ~10us (3 x s_sleep(127)
    //      = 3 x 8128 clk = ~10.2us @2.4GHz). Deterministic, no mem effects.
    if ((blockIdx.x >> 3) & 1) {
        #pragma unroll
        for (int t = 0; t < 3; ++t) __builtin_amdgcn_s_sleep(127);
    }

    __shared__ int    col_s[8][KNN];
    __shared__ float  ad_s[8][KNN];
    __shared__ float2 cw_s[8][KNN];   // packed {bitcast(col), w}

    const int tid  = threadIdx.x;
    const int j    = tid & 31;      // lane within half-wave = neighbor slot
    const int r    = tid >> 5;      // row-within-block, 0..7 (half-wave id)
    const int row0 = blockIdx.x * 8;
    const int row  = row0 + r;

    const float alpha = scalar_val(alpha_p);
    const float beta  = scalar_val(beta_p);

    // ---- Phase 0: neighbor ids; LDS copy kept for later phases ----
    const int col = idx[row * 64 + 1 + j];       // idxa0 = idx[:, 1:33]
    col_s[r][j] = col;

    // ---- Phase 1: distances, quad-per-column; cols via register shfl ----
    const float4* Y4 = (const float4*)Y;
    const float4* O4 = (const float4*)orthoH;
    const int p = j & 3;            // quad lane
    const int Q = j >> 2;           // quad id 0..7
    const int hbase = tid & 32;     // half-wave base within this wave

    const int c0 = __shfl(col, hbase | (0 * 8 + Q), 64);
    const int c1 = __shfl(col, hbase | (1 * 8 + Q), 64);
    const int c2 = __shfl(col, hbase | (2 * 8 + Q), 64);
    const int c3 = __shfl(col, hbase | (3 * 8 + Q), 64);

    float4 oy0 = Y4[(size_t)row * 16 + p +  0];
    float4 oy1 = Y4[(size_t)row * 16 + p +  4];
    float4 oy2 = Y4[(size_t)row * 16 + p +  8];
    float4 oy3 = Y4[(size_t)row * 16 + p + 12];
    float4 oo0 = O4[(size_t)row * 16 + p +  0];
    float4 oo1 = O4[(size_t)row * 16 + p +  4];
    float4 oo2 = O4[(size_t)row * 16 + p +  8];
    float4 oo3 = O4[(size_t)row * 16 + p + 12];

    const int cq[4] = {c0, c1, c2, c3};
    #pragma unroll
    for (int b = 0; b < 4; ++b) {
        const int cidx = b * 8 + Q;
        const int c = cq[b];
        float dY = 0.f, dO = 0.f;
        #define ACC_PH(ph, oy, oo)                                          \
        {                                                                   \
            float4 gY = Y4[(size_t)c * 16 + p + 4 * ph];                    \
            float4 gO = O4[(size_t)c * 16 + p + 4 * ph];                    \
            float ex = oy.x - gY.x, ey = oy.y - gY.y,                       \
                  ez = oy.z - gY.z, ew = oy.w - gY.w;                       \
            dY += ex * ex + ey * ey + ez * ez + ew * ew;                    \
            ex = oo.x - gO.x; ey = oo.y - gO.y;                             \
            ez = oo.z - gO.z; ew = oo.w - gO.w;                             \
            dO += ex * ex + ey * ey + ez * ez + ew * ew;                    \
        }
        ACC_PH(0, oy0, oo0)
        ACC_PH(1, oy1, oo1)
        ACC_PH(2, oy2, oo2)
        ACC_PH(3, oy3, oo3)
        #undef ACC_PH
        dY += __shfl_xor(dY, 1, 64);
        dY += __shfl_xor(dY, 2, 64);
        dO += __shfl_xor(dO, 1, 64);
        dO += __shfl_xor(dO, 2, 64);
        if (p == 0) {
            float dfv = sqrtf(dY + 1e-8f);          // dfi (from Y)
            float dxv = sqrtf(dO + 1e-8f);          // dxi (from ortho_H)
            ad_s[r][cidx] = -(dxv + beta * dfv) / (2.f * alpha);
        }
    }
    const float ad = ad_s[r][j];

    // ---- Phase 2: simplex projection (32 lanes = one row) ----
    float s = ad;
    #pragma unroll
    for (int mm = 1; mm <= 16; mm <<= 1) s += __shfl_xor(s, mm, 64);
    const float v0 = ad - s * (1.f / 32.f) + (1.f / 32.f);

    const unsigned long long halfsh = (unsigned long long)(tid & 32);
    const unsigned long long halfmask = 0xFFFFFFFFull << halfsh;
    float lam = 0.f;
    #pragma unroll 1
    for (int it = 0; it < MAXIT; ++it) {
        float v1 = v0 - lam;
        bool pos = v1 > 0.f;
        float pp = pos ? v1 : 0.f;
        #pragma unroll
        for (int mm = 1; mm <= 16; mm <<= 1) pp += __shfl_xor(pp, mm, 64);
        float c = (float)__popcll(__ballot(pos ? 1 : 0) & halfmask);
        float step = (pp - 1.f) / fmaxf(c, 1.f);
        lam += step;
        if (__all(fabsf(step) <= 1e-6f ? 1 : 0)) break;
    }
    const float w = fmaxf(v0 - lam, 0.f);

    // ---- Phase 3: publish raw (col, w); dedupe handled by owners below ----
    cw_s[r][j] = make_float2(__int_as_float(col), w);

    // ---- Phase 4: ballot-transpose -> mymask (which jj are mine) ----
    const int myowner = (col >> 2) & 31;
    unsigned mymask = 0u;
    #pragma unroll
    for (int o = 0; o < 32; ++o) {
        unsigned long long b = __ballot(myowner == o ? 1 : 0);
        if (j == o) mymask = (unsigned)(b >> halfsh);
    }

    // ---- Phase 5: slot-fill over my hits (ascending jj = np last-wins).
    // Duplicate col => same owner, same key: collapse in place, zero the
    // earlier entry's w in cw_s (for embs). key=(ss<<2)|pos, ss=c>>7, pos=c&3.
    unsigned k0 = ~0u, k1 = ~0u, k2 = ~0u, k3 = ~0u;
    float f0 = 0.f, f1 = 0.f, f2 = 0.f, f3 = 0.f;
    int j0 = 0, j1 = 0, j2 = 0, j3 = 0;
    int nhit = 0;
    unsigned ovmask = 0u;
    {
        unsigned mrem = mymask;
        while (mrem) {
            int jj = __ffs(mrem) - 1;
            mrem &= mrem - 1;
            float2 cw = cw_s[r][jj];
            int c = __float_as_int(cw.x);
            unsigned key = ((unsigned)(c >> 7) << 2) | (unsigned)(c & 3);
            float wv = cw.y;
            if      (nhit > 0 && key == k0) { cw_s[r][j0].y = 0.f; f0 = wv; j0 = jj; }
            else if (nhit > 1 && key == k1) { cw_s[r][j1].y = 0.f; f1 = wv; j1 = jj; }
            else if (nhit > 2 && key == k2) { cw_s[r][j2].y = 0.f; f2 = wv; j2 = jj; }
            else if (nhit > 3 && key == k3) { cw_s[r][j3].y = 0.f; f3 = wv; j3 = jj; }
            else if (nhit == 0) { k0 = key; f0 = wv; j0 = jj; nhit = 1; }
            else if (nhit == 1) { k1 = key; f1 = wv; j1 = jj; nhit = 2; }
            else if (nhit == 2) { k2 = key; f2 = wv; j2 = jj; nhit = 3; }
            else if (nhit == 3) { k3 = key; f3 = wv; j3 = jj; nhit = 4; }
            else { ovmask |= 1u << jj; }
        }
    }

    // ---- Phase 6: overflow rows fall back to exact full dedupe (rare) ----
    {
        unsigned long long ovb = __ballot(ovmask != 0u ? 1 : 0);
        if (((ovb >> halfsh) & 0xFFFFFFFFull) != 0ull) {
            bool dead = false;
            for (int jj2 = j + 1; jj2 < 32; ++jj2)
                dead |= (col_s[r][jj2] == col);
            cw_s[r][j] = make_float2(__int_as_float(col), dead ? 0.f : w);
        }
    }

    // ---- Phase 7: embs_hom[row] = sum_j w_j * semH[col_j] (pre-stream) ----
    {
        float2 acc = make_float2(0.f, 0.f);
        const float2* H2 = (const float2*)semH;
        #pragma unroll
        for (int jj = 0; jj < KNN; ++jj) {
            float2 cw = cw_s[r][jj];
            int   c   = __float_as_int(cw.x);
            float wv  = cw.y;
            float2 h = H2[(size_t)c * 32 + j];
            acc.x += wv * h.x;
            acc.y += wv * h.y;
        }
        ((float2*)embs)[(size_t)row * 32 + j] = acc;
    }

    // ---- Phase 8: Y passthrough ----
    {
        const float2* Y2 = (const float2*)(Y + (size_t)row0 * DDIM);
        float2* O2 = (float2*)(Yout + (size_t)row0 * DDIM);
        O2[tid] = Y2[tid];
    }

    // ---- Phase 9: merged zero+scatter stream (unconditional 64 float4/lane)
    {
        float4* Arow4 = (float4*)(A + (size_t)row * NROWS);
        #pragma unroll 4
        for (int ss = 0; ss < 64; ++ss) {
            float4 v = make_float4(0.f, 0.f, 0.f, 0.f);
            #define APPLY_SLOT(kk, ff)                                   \
                if ((kk >> 2) == (unsigned)ss) {                         \
                    int p_ = (int)(kk & 3u);                             \
                    v.x = (p_ == 0) ? ff : v.x;                          \
                    v.y = (p_ == 1) ? ff : v.y;                          \
                    v.z = (p_ == 2) ? ff : v.z;                          \
                    v.w = (p_ == 3) ? ff : v.w;                          \
                }
            APPLY_SLOT(k0, f0)
            APPLY_SLOT(k1, f1)
            APPLY_SLOT(k2, f2)
            APPLY_SLOT(k3, f3)
            #undef APPLY_SLOT
            Arow4[(ss << 5) + j] = v;
        }
    }

    // ---- Phase 10: overflow fixups (>4 distinct keys on a lane): ordered
    //      dword writes, ascending jj = np last-wins ----
    if (ovmask) {
        asm volatile("s_waitcnt vmcnt(0)" ::: "memory");
        unsigned m = ovmask;
        while (m) {
            int jj = __ffs(m) - 1;
            m &= m - 1;
            int c = col_s[r][jj];
            A[(size_t)row * NROWS + c] = cw_s[r][jj].y;
            asm volatile("s_waitcnt vmcnt(0)" ::: "memory");
        }
    }
}

extern "C" void kernel_launch(void* const* d_in, const int* in_sizes, int n_in,
                              void* d_out, int out_size, void* d_ws, size_t ws_size,
                              hipStream_t stream) {
    const float* Y      = (const float*)d_in[0];
    const float* semH   = (const float*)d_in[1];
    const float* orthoH = (const float*)d_in[2];
    const int*   idx    = (const int*)d_in[3];
    const void*  alpha  = d_in[4];
    const void*  beta   = d_in[5];

    float* out  = (float*)d_out;
    float* embs = out;                                   // N*D
    float* A    = out + (size_t)NROWS * DDIM;            // N*N
    float* Yout = A + (size_t)NROWS * NROWS;             // N*D

    school_fused_kernel<<<NROWS / 8, 256, 0, stream>>>(
        Y, semH, orthoH, idx, alpha, beta, embs, A, Yout);
}

// Round 24
// 56.653 us; speedup vs baseline: 1.1338x; 1.1338x over previous
//
#include <hip/hip_runtime.h>

#define NROWS 8192
#define DDIM  64
#define KNN   32
#define MAXIT 100

// alpha/beta arrive as 1-element arrays; robust to int32 or float32 encoding.
__device__ __forceinline__ float scalar_val(const void* p) {
    int iv = *(const int*)p;
    if (iv > -1000000 && iv < 1000000) return (float)iv;
    return *(const float*)p;
}

// CHAMPION (R16, 56.8us). One block = 8 rows, half-wave (32 lanes) per row.
// Structure: loads+compute front (distances via quad-per-column gathers with
// shfl-transposed addresses; ballot Newton; ballot-transpose dedupe/slot-fill;
// embs BEFORE the store stream -- in-order vmcnt!), then one unconditional
// merged zero+scatter float4 stream over the row, then rare ordered fixups.
// 56.8us = 39.5us mandatory A-drain (fill rate) + ~17us L3-read-bound front.
__global__ __launch_bounds__(256, 4) void school_fused_kernel(
    const float* __restrict__ Y,
    const float* __restrict__ semH,
    const float* __restrict__ orthoH,
    const int*   __restrict__ idx,
    const void*  alpha_p,
    const void*  beta_p,
    float* __restrict__ embs,   // N*D
    float* __restrict__ A,      // N*N
    float* __restrict__ Yout)   // N*D
{
    __shared__ int    col_s[8][KNN];
    __shared__ float  ad_s[8][KNN];
    __shared__ float2 cw_s[8][KNN];   // packed {bitcast(col), w}

    const int tid  = threadIdx.x;
    const int j    = tid & 31;      // lane within half-wave = neighbor slot
    const int r    = tid >> 5;      // row-within-block, 0..7 (half-wave id)
    const int row0 = blockIdx.x * 8;
    const int row  = row0 + r;

    const float alpha = scalar_val(alpha_p);
    const float beta  = scalar_val(beta_p);

    // ---- Phase 0: neighbor ids; LDS copy kept for later phases ----
    const int col = idx[row * 64 + 1 + j];       // idxa0 = idx[:, 1:33]
    col_s[r][j] = col;

    // ---- Phase 1: distances, quad-per-column; cols via register shfl ----
    const float4* Y4 = (const float4*)Y;
    const float4* O4 = (const float4*)orthoH;
    const int p = j & 3;            // quad lane
    const int Q = j >> 2;           // quad id 0..7
    const int hbase = tid & 32;     // half-wave base within this wave

    // all 4 column ids for this quad, via cross-lane reg transpose (no LDS)
    const int c0 = __shfl(col, hbase | (0 * 8 + Q), 64);
    const int c1 = __shfl(col, hbase | (1 * 8 + Q), 64);
    const int c2 = __shfl(col, hbase | (2 * 8 + Q), 64);
    const int c3 = __shfl(col, hbase | (3 * 8 + Q), 64);

    float4 oy0 = Y4[(size_t)row * 16 + p +  0];
    float4 oy1 = Y4[(size_t)row * 16 + p +  4];
    float4 oy2 = Y4[(size_t)row * 16 + p +  8];
    float4 oy3 = Y4[(size_t)row * 16 + p + 12];
    float4 oo0 = O4[(size_t)row * 16 + p +  0];
    float4 oo1 = O4[(size_t)row * 16 + p +  4];
    float4 oo2 = O4[(size_t)row * 16 + p +  8];
    float4 oo3 = O4[(size_t)row * 16 + p + 12];

    const int cq[4] = {c0, c1, c2, c3};
    #pragma unroll
    for (int b = 0; b < 4; ++b) {
        const int cidx = b * 8 + Q;
        const int c = cq[b];
        float dY = 0.f, dO = 0.f;
        #define ACC_PH(ph, oy, oo)                                          \
        {                                                                   \
            float4 gY = Y4[(size_t)c * 16 + p + 4 * ph];                    \
            float4 gO = O4[(size_t)c * 16 + p + 4 * ph];                    \
            float ex = oy.x - gY.x, ey = oy.y - gY.y,                       \
                  ez = oy.z - gY.z, ew = oy.w - gY.w;                       \
            dY += ex * ex + ey * ey + ez * ez + ew * ew;                    \
            ex = oo.x - gO.x; ey = oo.y - gO.y;                             \
            ez = oo.z - gO.z; ew = oo.w - gO.w;                             \
            dO += ex * ex + ey * ey + ez * ez + ew * ew;                    \
        }
        ACC_PH(0, oy0, oo0)
        ACC_PH(1, oy1, oo1)
        ACC_PH(2, oy2, oo2)
        ACC_PH(3, oy3, oo3)
        #undef ACC_PH
        dY += __shfl_xor(dY, 1, 64);
        dY += __shfl_xor(dY, 2, 64);
        dO += __shfl_xor(dO, 1, 64);
        dO += __shfl_xor(dO, 2, 64);
        if (p == 0) {
            float dfv = sqrtf(dY + 1e-8f);          // dfi (from Y)
            float dxv = sqrtf(dO + 1e-8f);          // dxi (from ortho_H)
            ad_s[r][cidx] = -(dxv + beta * dfv) / (2.f * alpha);
        }
    }
    const float ad = ad_s[r][j];

    // ---- Phase 2: simplex projection (32 lanes = one row) ----
    float s = ad;
    #pragma unroll
    for (int mm = 1; mm <= 16; mm <<= 1) s += __shfl_xor(s, mm, 64);
    const float v0 = ad - s * (1.f / 32.f) + (1.f / 32.f);

    const unsigned long long halfsh = (unsigned long long)(tid & 32);
    const unsigned long long halfmask = 0xFFFFFFFFull << halfsh;
    float lam = 0.f;
    #pragma unroll 1
    for (int it = 0; it < MAXIT; ++it) {
        float v1 = v0 - lam;
        bool pos = v1 > 0.f;
        float pp = pos ? v1 : 0.f;
        #pragma unroll
        for (int mm = 1; mm <= 16; mm <<= 1) pp += __shfl_xor(pp, mm, 64);
        float c = (float)__popcll(__ballot(pos ? 1 : 0) & halfmask);
        float step = (pp - 1.f) / fmaxf(c, 1.f);
        lam += step;
        if (__all(fabsf(step) <= 1e-6f ? 1 : 0)) break;
    }
    const float w = fmaxf(v0 - lam, 0.f);

    // ---- Phase 3: publish raw (col, w); dedupe handled by owners below ----
    cw_s[r][j] = make_float2(__int_as_float(col), w);

    // ---- Phase 4: ballot-transpose -> mymask (which jj are mine) ----
    const int myowner = (col >> 2) & 31;
    unsigned mymask = 0u;
    #pragma unroll
    for (int o = 0; o < 32; ++o) {
        unsigned long long b = __ballot(myowner == o ? 1 : 0);
        if (j == o) mymask = (unsigned)(b >> halfsh);
    }

    // ---- Phase 5: slot-fill over my hits (ascending jj = np last-wins).
    // Duplicate col => same owner, same key: collapse in place, zero the
    // earlier entry's w in cw_s (for embs). key=(ss<<2)|pos, ss=c>>7, pos=c&3.
    unsigned k0 = ~0u, k1 = ~0u, k2 = ~0u, k3 = ~0u;
    float f0 = 0.f, f1 = 0.f, f2 = 0.f, f3 = 0.f;
    int j0 = 0, j1 = 0, j2 = 0, j3 = 0;
    int nhit = 0;
    unsigned ovmask = 0u;
    {
        unsigned mrem = mymask;
        while (mrem) {
            int jj = __ffs(mrem) - 1;
            mrem &= mrem - 1;
            float2 cw = cw_s[r][jj];
            int c = __float_as_int(cw.x);
            unsigned key = ((unsigned)(c >> 7) << 2) | (unsigned)(c & 3);
            float wv = cw.y;
            if      (nhit > 0 && key == k0) { cw_s[r][j0].y = 0.f; f0 = wv; j0 = jj; }
            else if (nhit > 1 && key == k1) { cw_s[r][j1].y = 0.f; f1 = wv; j1 = jj; }
            else if (nhit > 2 && key == k2) { cw_s[r][j2].y = 0.f; f2 = wv; j2 = jj; }
            else if (nhit > 3 && key == k3) { cw_s[r][j3].y = 0.f; f3 = wv; j3 = jj; }
            else if (nhit == 0) { k0 = key; f0 = wv; j0 = jj; nhit = 1; }
            else if (nhit == 1) { k1 = key; f1 = wv; j1 = jj; nhit = 2; }
            else if (nhit == 2) { k2 = key; f2 = wv; j2 = jj; nhit = 3; }
            else if (nhit == 3) { k3 = key; f3 = wv; j3 = jj; nhit = 4; }
            else { ovmask |= 1u << jj; }
        }
    }

    // ---- Phase 6: overflow rows fall back to exact full dedupe (rare) ----
    {
        unsigned long long ovb = __ballot(ovmask != 0u ? 1 : 0);
        if (((ovb >> halfsh) & 0xFFFFFFFFull) != 0ull) {
            bool dead = false;
            for (int jj2 = j + 1; jj2 < 32; ++jj2)
                dead |= (col_s[r][jj2] == col);
            cw_s[r][j] = make_float2(__int_as_float(col), dead ? 0.f : w);
        }
    }

    // ---- Phase 7: embs_hom[row] = sum_j w_j * semH[col_j] (pre-stream) ----
    {
        float2 acc = make_float2(0.f, 0.f);
        const float2* H2 = (const float2*)semH;
        #pragma unroll
        for (int jj = 0; jj < KNN; ++jj) {
            float2 cw = cw_s[r][jj];
            int   c   = __float_as_int(cw.x);
            float wv  = cw.y;
            float2 h = H2[(size_t)c * 32 + j];
            acc.x += wv * h.x;
            acc.y += wv * h.y;
        }
        ((float2*)embs)[(size_t)row * 32 + j] = acc;
    }

    // ---- Phase 8: Y passthrough ----
    {
        const float2* Y2 = (const float2*)(Y + (size_t)row0 * DDIM);
        float2* O2 = (float2*)(Yout + (size_t)row0 * DDIM);
        O2[tid] = Y2[tid];
    }

    // ---- Phase 9: merged zero+scatter stream (unconditional 64 float4/lane)
    {
        float4* Arow4 = (float4*)(A + (size_t)row * NROWS);
        #pragma unroll 4
        for (int ss = 0; ss < 64; ++ss) {
            float4 v = make_float4(0.f, 0.f, 0.f, 0.f);
            #define APPLY_SLOT(kk, ff)                                   \
                if ((kk >> 2) == (unsigned)ss) {                         \
                    int p_ = (int)(kk & 3u);                             \
                    v.x = (p_ == 0) ? ff : v.x;                          \
                    v.y = (p_ == 1) ? ff : v.y;                          \
                    v.z = (p_ == 2) ? ff : v.z;                          \
                    v.w = (p_ == 3) ? ff : v.w;                          \
                }
            APPLY_SLOT(k0, f0)
            APPLY_SLOT(k1, f1)
            APPLY_SLOT(k2, f2)
            APPLY_SLOT(k3, f3)
            #undef APPLY_SLOT
            Arow4[(ss << 5) + j] = v;
        }
    }

    // ---- Phase 10: overflow fixups (>4 distinct keys on a lane): ordered
    //      dword writes, ascending jj = np last-wins ----
    if (ovmask) {
        asm volatile("s_waitcnt vmcnt(0)" ::: "memory");
        unsigned m = ovmask;
        while (m) {
            int jj = __ffs(m) - 1;
            m &= m - 1;
            int c = col_s[r][jj];
            A[(size_t)row * NROWS + c] = cw_s[r][jj].y;
            asm volatile("s_waitcnt vmcnt(0)" ::: "memory");
        }
    }
}

extern "C" void kernel_launch(void* const* d_in, const int* in_sizes, int n_in,
                              void* d_out, int out_size, void* d_ws, size_t ws_size,
                              hipStream_t stream) {
    const float* Y      = (const float*)d_in[0];
    const float* semH   = (const float*)d_in[1];
    const float* orthoH = (const float*)d_in[2];
    const int*   idx    = (const int*)d_in[3];
    const void*  alpha  = d_in[4];
    const void*  beta   = d_in[5];

    float* out  = (float*)d_out;
    float* embs = out;                                   // N*D
    float* A    = out + (size_t)NROWS * DDIM;            // N*N
    float* Yout = A + (size_t)NROWS * NROWS;             // N*D

    school_fused_kernel<<<NROWS / 8, 256, 0, stream>>>(
        Y, semH, orthoH, idx, alpha, beta, embs, A, Yout);
}